// Round 9
// baseline (226.979 us; speedup 1.0000x reference)
//
#include <hip/hip_runtime.h>
#include <math.h>

// Chamfer distance, N=M=16384, D=3, fp32 — R11: 32x32x16 MFMA, amortized.
// R10 worked (43.2us, bit-clean) but NJT=16 made the block-end machinery
// (row butterfly + A/B split build) ~35% of loop work, and the per-iter
// colacc LDS rmw added 3 DS ops + a latency chain per iter. R11:
//  - JCHUNK 1024 (NJT=32): finish/loop ratio 35% -> 17%
//  - col-min: shfl_xor(32)-merge per iter into 8 NAMED regs, batch-flushed
//    as pure ds_write every 8 iters (write-once; no LDS reads in loop)
//  - fully explicit 4x8 unroll, static indices only (no scratch risk)
// Slot convention (verified bit-clean in R9/R10): k0-8 2-way-split cross
// terms, k9-11 |a|^2 3-way (x1 on B), k12-14 |b|^2 3-way (x1 on A).

typedef short s16x8 __attribute__((ext_vector_type(8)));
typedef float f32x16 __attribute__((ext_vector_type(16)));

constexpr int N       = 16384;
constexpr int THREADS = 256;           // 4 waves
constexpr int ISTRIP  = 256;           // i's per block (4 waves x 2 tiles x 32)
constexpr int NSTRIPS = N / ISTRIP;    // 64
constexpr int JCHUNK  = 1024;          // j's per block
constexpr int NCHUNKS = N / JCHUNK;    // 16
constexpr int NJT     = JCHUNK / 32;   // 32 j-tiles per block
constexpr int CBW     = 1040;          // cbuf row stride (1024+16)
constexpr float INF_F = 3.402823466e+38f;
constexpr short ONE_BF = (short)0x3F80;  // bf16(1.0)

static __device__ __forceinline__ short bf_hi(float x) {  // RN bf16 bits
  unsigned u = __float_as_uint(x);
  unsigned r = (u + 0x7fffu + ((u >> 16) & 1u)) >> 16;
  return (short)r;
}
static __device__ __forceinline__ float bf_val(short h) {
  return __uint_as_float(((unsigned)(unsigned short)h) << 16);
}

__global__ __launch_bounds__(THREADS, 3) void chamfer_mfma(
    const float* __restrict__ p1, const float* __restrict__ p2,
    float* __restrict__ rowPart, float* __restrict__ colPart,
    float* __restrict__ out) {
  __shared__ s16x8 bfrag[NJT * 64];   // [jtile][lane] B frags, 32 KB
  __shared__ float cbuf[4 * CBW];     // [wave][1024+pad] col-mins, 16.6 KB

  const int tid  = threadIdx.x;
  const int l    = tid & 63;
  const int w    = tid >> 6;
  const int cl   = l & 31;   // col-in-tile (B,C) / row-in-tile (A)
  const int half = l >> 5;   // k-octet owner
  const int bid  = blockIdx.x;
  const int strip = bid & (NSTRIPS - 1);
  const int chunk = bid >> 6;            // NSTRIPS == 64
  const int i0 = strip * ISTRIP;
  const int j0 = chunk * JCHUNK;

  if (bid == 0 && tid == 0) *out = 0.0f;  // ordered before sum's atomics

  // ---- stage B fragments: 4 points per thread ----
  for (int jl = tid; jl < JCHUNK; jl += THREADS) {
    const float* bp = p2 + (size_t)(j0 + jl) * 3;
    const float ox = bp[0], oy = bp[1], oz = bp[2];
    const float sb = fmaf(ox, ox, fmaf(oy, oy, oz * oz));
    const float bx = -2.0f * ox, by = -2.0f * oy, bz = -2.0f * oz;
    const short bhx = bf_hi(bx), blx = bf_hi(bx - bf_val(bhx));
    const short bhy = bf_hi(by), bly = bf_hi(by - bf_val(bhy));
    const short bhz = bf_hi(bz), blz = bf_hi(bz - bf_val(bhz));
    const short sbh = bf_hi(sb);
    const float r1 = sb - bf_val(sbh);
    const short sbm = bf_hi(r1);
    const short sbl = bf_hi(r1 - bf_val(sbm));
    const int jt = jl >> 5, c = jl & 31;
    bfrag[jt * 64 + c]      = (s16x8){bhx, blx, bhx, bhy, bly, bhy, bhz, blz};
    bfrag[jt * 64 + 32 + c] = (s16x8){bhz, ONE_BF, ONE_BF, ONE_BF,
                                      sbh, sbm, sbl, 0};
  }

  // ---- A fragments: 2 row-tiles (64 i's) per wave, in registers ----
#define ABUILD(t, AF)                                                        \
  s16x8 AF;                                                                  \
  {                                                                          \
    const float* ap = p1 + (size_t)(i0 + w * 64 + (t)*32 + cl) * 3;          \
    const float x = ap[0], y = ap[1], z = ap[2];                             \
    const float sa = fmaf(x, x, fmaf(y, y, z * z));                          \
    const short ahx = bf_hi(x), alx = bf_hi(x - bf_val(ahx));                \
    const short ahy = bf_hi(y), aly = bf_hi(y - bf_val(ahy));                \
    const short ahz = bf_hi(z), alz = bf_hi(z - bf_val(ahz));                \
    const short sah = bf_hi(sa);                                             \
    const float q1 = sa - bf_val(sah);                                       \
    const short sam = bf_hi(q1);                                             \
    const short sal = bf_hi(q1 - bf_val(sam));                               \
    AF = half ? (s16x8){alz, sah, sam, sal, ONE_BF, ONE_BF, ONE_BF, 0}       \
              : (s16x8){ahx, ahx, alx, ahy, ahy, aly, ahz, ahz};             \
  }
  ABUILD(0, A0) ABUILD(1, A1)
#undef ABUILD

  f32x16 RAa, RAb;
#pragma unroll
  for (int r = 0; r < 16; ++r) { RAa[r] = INF_F; RAb[r] = INF_F; }
  const f32x16 zero16 = RAa - RAa;  // {0,...}

  __syncthreads();

  // jt-loop, fully explicit 4 groups x 8 steps. Per step: 1 ds_read_b128,
  // 2 MFMA, 32 RA-min, 31 col-tree min, 1 shfl_xor + 1 min; col result to a
  // NAMED reg. Per group: 8 pure ds_write_b32 (write-once, no rmw).
  float CM0, CM1, CM2, CM3, CM4, CM5, CM6, CM7;
#define JSTEP_(jt, CMq)                                                      \
  {                                                                          \
    const s16x8 bf = bfrag[(jt)*64 + l];                                     \
    const f32x16 C0 =                                                        \
        __builtin_amdgcn_mfma_f32_32x32x16_bf16(A0, bf, zero16, 0, 0, 0);    \
    const f32x16 C1 =                                                        \
        __builtin_amdgcn_mfma_f32_32x32x16_bf16(A1, bf, zero16, 0, 0, 0);    \
    RAa = __builtin_elementwise_min(RAa, C0);                                \
    RAb = __builtin_elementwise_min(RAb, C1);                                \
    const f32x16 t = __builtin_elementwise_min(C0, C1);                      \
    const float u0 = fminf(fminf(t[0], t[1]), fminf(t[2], t[3]));            \
    const float u1 = fminf(fminf(t[4], t[5]), fminf(t[6], t[7]));            \
    const float u2 = fminf(fminf(t[8], t[9]), fminf(t[10], t[11]));          \
    const float u3 = fminf(fminf(t[12], t[13]), fminf(t[14], t[15]));        \
    float cm = fminf(fminf(u0, u1), fminf(u2, u3));                          \
    cm = fminf(cm, __shfl_xor(cm, 32, 64));                                  \
    CMq = cm;                                                                \
  }
#define JGROUP(g)                                                            \
  JSTEP_((g)*8 + 0, CM0) JSTEP_((g)*8 + 1, CM1)                              \
  JSTEP_((g)*8 + 2, CM2) JSTEP_((g)*8 + 3, CM3)                              \
  JSTEP_((g)*8 + 4, CM4) JSTEP_((g)*8 + 5, CM5)                              \
  JSTEP_((g)*8 + 6, CM6) JSTEP_((g)*8 + 7, CM7)                              \
  {                                                                          \
    float* cb = &cbuf[w * CBW + (g)*8 * 32 + cl];                            \
    cb[0 * 32] = CM0; cb[1 * 32] = CM1; cb[2 * 32] = CM2; cb[3 * 32] = CM3;  \
    cb[4 * 32] = CM4; cb[5 * 32] = CM5; cb[6 * 32] = CM6; cb[7 * 32] = CM7;  \
  }
  JGROUP(0) JGROUP(1) JGROUP(2) JGROUP(3)
#undef JGROUP
#undef JSTEP_

  // ---- row-min finish: butterfly over the 32 col-lanes of each half ----
#define RFIN(RV, t)                                                          \
  _Pragma("unroll") for (int r = 0; r < 16; ++r) {                           \
    float v = RV[r];                                                         \
    v = fminf(v, __shfl_xor(v, 1, 64));                                      \
    v = fminf(v, __shfl_xor(v, 2, 64));                                      \
    v = fminf(v, __shfl_xor(v, 4, 64));                                      \
    v = fminf(v, __shfl_xor(v, 8, 64));                                      \
    v = fminf(v, __shfl_xor(v, 16, 64));                                     \
    if (cl == 0) {                                                           \
      const int row = (r & 3) + 8 * (r >> 2) + 4 * half;                     \
      rowPart[(size_t)chunk * N + i0 + w * 64 + (t)*32 + row] = v;           \
    }                                                                        \
  }
  RFIN(RAa, 0) RFIN(RAb, 1)
#undef RFIN

  // ---- col-min finish: merge the 4 wave rows of cbuf ----
  __syncthreads();
  for (int c = tid; c < JCHUNK; c += THREADS) {
    const float m = fminf(fminf(cbuf[c], cbuf[CBW + c]),
                          fminf(cbuf[2 * CBW + c], cbuf[3 * CBW + c]));
    colPart[(size_t)strip * N + j0 + c] = m;
  }
}

// One thread per point (2*16384): min over partials (d^2 complete — norms
// were inside the MFMA), sqrt, block-sum, one atomicAdd into out[0].
__global__ __launch_bounds__(THREADS) void chamfer_sum(
    const float* __restrict__ rowPart, const float* __restrict__ colPart,
    float* __restrict__ out) {
  const int p = blockIdx.x * THREADS + threadIdx.x;  // 0..32767
  float m0 = INF_F, m1 = INF_F, m2 = INF_F, m3 = INF_F;
  if (p < N) {
    const float* rp = rowPart + p;
    for (int c = 0; c < NCHUNKS; c += 4) {
      m0 = fminf(m0, rp[(size_t)(c + 0) * N]);
      m1 = fminf(m1, rp[(size_t)(c + 1) * N]);
      m2 = fminf(m2, rp[(size_t)(c + 2) * N]);
      m3 = fminf(m3, rp[(size_t)(c + 3) * N]);
    }
  } else {
    const float* cp = colPart + (p - N);
    for (int s = 0; s < NSTRIPS; s += 4) {
      m0 = fminf(m0, cp[(size_t)(s + 0) * N]);
      m1 = fminf(m1, cp[(size_t)(s + 1) * N]);
      m2 = fminf(m2, cp[(size_t)(s + 2) * N]);
      m3 = fminf(m3, cp[(size_t)(s + 3) * N]);
    }
  }
  float d = sqrtf(fmaxf(fminf(fminf(m0, m1), fminf(m2, m3)), 0.0f));

  for (int off = 32; off > 0; off >>= 1) d += __shfl_down(d, off, 64);
  __shared__ float red[THREADS / 64];
  const int wave = threadIdx.x >> 6;
  const int lane = threadIdx.x & 63;
  if (lane == 0) red[wave] = d;
  __syncthreads();
  if (threadIdx.x == 0) {
    float s = 0.0f;
    for (int wv = 0; wv < THREADS / 64; ++wv) s += red[wv];
    atomicAdd(out, s);
  }
}

extern "C" void kernel_launch(void* const* d_in, const int* in_sizes, int n_in,
                              void* d_out, int out_size, void* d_ws, size_t ws_size,
                              hipStream_t stream) {
  const float* p1 = (const float*)d_in[0];
  const float* p2 = (const float*)d_in[1];
  float* out = (float*)d_out;
  float* ws = (float*)d_ws;

  // ws: rowPart[NCHUNKS=16][N] (1MB) + colPart[NSTRIPS=64][N] (4MB).
  float* rowPart = ws;
  float* colPart = ws + (size_t)NCHUNKS * N;

  chamfer_mfma<<<dim3(NSTRIPS * NCHUNKS), THREADS, 0, stream>>>(
      p1, p2, rowPart, colPart, out);
  chamfer_sum<<<dim3((2 * N) / THREADS), THREADS, 0, stream>>>(rowPart, colPart,
                                                               out);
}

// Round 10
// 88.113 us; speedup vs baseline: 2.5760x; 2.5760x over previous
//
#include <hip/hip_runtime.h>
#include <math.h>

// Chamfer distance, N=M=16384, D=3, fp32 — R12: MFMA core + DS-pipe diet.
// R10 audit: the 43us plateau was the per-CU DS pipe (~292 DS instr/wave:
// colacc rmw, 160 bpermutes in the row butterfly, broadcast reads), NOT
// VALU (hand count 18k cy vs 61k "busy"). R11's full unroll spilled
// (645MB scratch) — loop stays rolled. R12 cuts DS/wave to ~176:
//  - JCHUNK 1024 (NJT=32): all finish costs amortize 2x
//  - col-min: tree + 1 shfl + write-once ds_write_b32 (no rmw)
//  - row-min finish: LDS transpose-reduce (8 ds_write_b128 + 32 ds_read_b32)
//    instead of 160 ds_bpermute; region ALIASES bfrag after one barrier
//  - explicit zero16 (R10's RAa-RAa relied on constant folding)
// Slot packing (bit-clean since R9): k0-8 2-way-split cross terms,
// k9-11 |a|^2 3-way (x1 on B), k12-14 |b|^2 3-way (x1 on A).

typedef short s16x8 __attribute__((ext_vector_type(8)));
typedef float f32x16 __attribute__((ext_vector_type(16)));

constexpr int N       = 16384;
constexpr int THREADS = 256;           // 4 waves
constexpr int ISTRIP  = 256;           // i's per block (4 waves x 2 tiles x 32)
constexpr int NSTRIPS = N / ISTRIP;    // 64
constexpr int JCHUNK  = 1024;          // j's per block
constexpr int NCHUNKS = N / JCHUNK;    // 16
constexpr int NJT     = JCHUNK / 32;   // 32 j-tiles
constexpr int CBW     = 1040;          // cbuf row stride (1024+16)
constexpr float INF_F = 3.402823466e+38f;
constexpr short ONE_BF = (short)0x3F80;  // bf16(1.0)

static __device__ __forceinline__ short bf_hi(float x) {  // RN bf16 bits
  unsigned u = __float_as_uint(x);
  unsigned r = (u + 0x7fffu + ((u >> 16) & 1u)) >> 16;
  return (short)r;
}
static __device__ __forceinline__ float bf_val(short h) {
  return __uint_as_float(((unsigned)(unsigned short)h) << 16);
}

__global__ __launch_bounds__(THREADS, 3) void chamfer_mfma(
    const float* __restrict__ p1, const float* __restrict__ p2,
    float* __restrict__ rowPart, float* __restrict__ colPart,
    float* __restrict__ out) {
  // smem[0..8191]      : bfrag (32KB) during loop; rmt (32KB) after barrier
  // smem[8192..12351]  : cbuf[4][1040] col-min partials (16.25KB)
  __shared__ __align__(16) float smem[12352];
  s16x8* const bfrag = (s16x8*)smem;          // [NJT][64]
  float* const rmt   = smem;                  // [4][2][32 cl][32 slot]
  float* const cbuf  = smem + 8192;           // [4][CBW]

  const int tid  = threadIdx.x;
  const int l    = tid & 63;
  const int w    = tid >> 6;
  const int cl   = l & 31;   // col-in-tile (B,C) / row-in-tile (A)
  const int half = l >> 5;   // k-octet owner
  const int bid  = blockIdx.x;
  const int strip = bid & (NSTRIPS - 1);
  const int chunk = bid >> 6;            // NSTRIPS == 64
  const int i0 = strip * ISTRIP;
  const int j0 = chunk * JCHUNK;

  if (bid == 0 && tid == 0) *out = 0.0f;  // ordered before sum's atomics

  // ---- stage B fragments: 4 points per thread ----
  for (int jl = tid; jl < JCHUNK; jl += THREADS) {
    const float* bp = p2 + (size_t)(j0 + jl) * 3;
    const float ox = bp[0], oy = bp[1], oz = bp[2];
    const float sb = fmaf(ox, ox, fmaf(oy, oy, oz * oz));
    const float bx = -2.0f * ox, by = -2.0f * oy, bz = -2.0f * oz;
    const short bhx = bf_hi(bx), blx = bf_hi(bx - bf_val(bhx));
    const short bhy = bf_hi(by), bly = bf_hi(by - bf_val(bhy));
    const short bhz = bf_hi(bz), blz = bf_hi(bz - bf_val(bhz));
    const short sbh = bf_hi(sb);
    const float r1 = sb - bf_val(sbh);
    const short sbm = bf_hi(r1);
    const short sbl = bf_hi(r1 - bf_val(sbm));
    const int jt = jl >> 5, c = jl & 31;
    bfrag[jt * 64 + c]      = (s16x8){bhx, blx, bhx, bhy, bly, bhy, bhz, blz};
    bfrag[jt * 64 + 32 + c] = (s16x8){bhz, ONE_BF, ONE_BF, ONE_BF,
                                      sbh, sbm, sbl, 0};
  }

  // ---- A fragments: 2 row-tiles (64 i's) per wave, in registers ----
#define ABUILD(t, AF)                                                        \
  s16x8 AF;                                                                  \
  {                                                                          \
    const float* ap = p1 + (size_t)(i0 + w * 64 + (t)*32 + cl) * 3;          \
    const float x = ap[0], y = ap[1], z = ap[2];                             \
    const float sa = fmaf(x, x, fmaf(y, y, z * z));                          \
    const short ahx = bf_hi(x), alx = bf_hi(x - bf_val(ahx));                \
    const short ahy = bf_hi(y), aly = bf_hi(y - bf_val(ahy));                \
    const short ahz = bf_hi(z), alz = bf_hi(z - bf_val(ahz));                \
    const short sah = bf_hi(sa);                                             \
    const float q1 = sa - bf_val(sah);                                       \
    const short sam = bf_hi(q1);                                             \
    const short sal = bf_hi(q1 - bf_val(sam));                               \
    AF = half ? (s16x8){alz, sah, sam, sal, ONE_BF, ONE_BF, ONE_BF, 0}       \
              : (s16x8){ahx, ahx, alx, ahy, ahy, aly, ahz, ahz};             \
  }
  ABUILD(0, A0) ABUILD(1, A1)
#undef ABUILD

  f32x16 RAa, RAb, zero16;
#pragma unroll
  for (int r = 0; r < 16; ++r) { RAa[r] = INF_F; RAb[r] = INF_F; zero16[r] = 0.0f; }

  __syncthreads();

  // jt-loop (rolled; unroll 2). Per iter: 1 ds_read_b128, 2 MFMA,
  // 32 row-min, 31 col-tree min, 1 shfl, 1 write-once ds_write_b32.
  float* const cwr = &cbuf[w * CBW + cl];
#pragma unroll 2
  for (int jt = 0; jt < NJT; ++jt) {
    const s16x8 bf = bfrag[jt * 64 + l];
    const f32x16 C0 =
        __builtin_amdgcn_mfma_f32_32x32x16_bf16(A0, bf, zero16, 0, 0, 0);
    const f32x16 C1 =
        __builtin_amdgcn_mfma_f32_32x32x16_bf16(A1, bf, zero16, 0, 0, 0);
    RAa = __builtin_elementwise_min(RAa, C0);
    RAb = __builtin_elementwise_min(RAb, C1);
    const f32x16 t = __builtin_elementwise_min(C0, C1);
    const float u0 = fminf(fminf(t[0], t[1]), fminf(t[2], t[3]));
    const float u1 = fminf(fminf(t[4], t[5]), fminf(t[6], t[7]));
    const float u2 = fminf(fminf(t[8], t[9]), fminf(t[10], t[11]));
    const float u3 = fminf(fminf(t[12], t[13]), fminf(t[14], t[15]));
    float cm = fminf(fminf(u0, u1), fminf(u2, u3));
    cm = fminf(cm, __shfl_xor(cm, 32, 64));  // both halves now hold the min
    cwr[jt * 32] = cm;  // same value from both halves: benign
  }

  __syncthreads();  // all bfrag reads done -> rmt may alias it

  // ---- row-min finish via LDS transpose (no bpermute storm) ----
  // write: lane (cl,half) packs its 16 RA values per tile at
  //        rmt[((w*2+tile)*32+cl)*32 + half*16 .. +15]  (4x ds_write_b128)
  {
    float* ra = &rmt[((w * 2 + 0) * 32 + cl) * 32 + half * 16];
    *(float4*)(ra + 0)  = make_float4(RAa[0], RAa[1], RAa[2], RAa[3]);
    *(float4*)(ra + 4)  = make_float4(RAa[4], RAa[5], RAa[6], RAa[7]);
    *(float4*)(ra + 8)  = make_float4(RAa[8], RAa[9], RAa[10], RAa[11]);
    *(float4*)(ra + 12) = make_float4(RAa[12], RAa[13], RAa[14], RAa[15]);
    float* rb = &rmt[((w * 2 + 1) * 32 + cl) * 32 + half * 16];
    *(float4*)(rb + 0)  = make_float4(RAb[0], RAb[1], RAb[2], RAb[3]);
    *(float4*)(rb + 4)  = make_float4(RAb[4], RAb[5], RAb[6], RAb[7]);
    *(float4*)(rb + 8)  = make_float4(RAb[8], RAb[9], RAb[10], RAb[11]);
    *(float4*)(rb + 12) = make_float4(RAb[12], RAb[13], RAb[14], RAb[15]);
  }
  // read: lane l of the wave reduces (tile=l>>5, slot=l&31) over 32 cls.
  // bank(addr) = slot%32 -> all 32 slots distinct banks; tiles 2-way (free).
  // Wave-local region: in-order DS within a wave, no extra barrier needed.
  {
    const int tl = l >> 5;
    const int s  = l & 31;
    const float* rp = &rmt[((w * 2 + tl) * 32) * 32 + s];
    float m = rp[0];
#pragma unroll
    for (int k = 1; k < 32; ++k) m = fminf(m, rp[k * 32]);
    const int r = s & 15, hh = s >> 4;
    const int row = (r & 3) + 8 * (r >> 2) + 4 * hh;
    rowPart[(size_t)chunk * N + i0 + w * 64 + tl * 32 + row] = m;
  }

  // ---- col-min finish: merge the 4 wave rows of cbuf ----
  for (int c = tid; c < JCHUNK; c += THREADS) {
    const float m = fminf(fminf(cbuf[c], cbuf[CBW + c]),
                          fminf(cbuf[2 * CBW + c], cbuf[3 * CBW + c]));
    colPart[(size_t)strip * N + j0 + c] = m;
  }
}

// One thread per point (2*16384): min over partials (d^2 complete — norms
// were inside the MFMA), sqrt, block-sum, one atomicAdd into out[0].
__global__ __launch_bounds__(THREADS) void chamfer_sum(
    const float* __restrict__ rowPart, const float* __restrict__ colPart,
    float* __restrict__ out) {
  const int p = blockIdx.x * THREADS + threadIdx.x;  // 0..32767
  float m0 = INF_F, m1 = INF_F, m2 = INF_F, m3 = INF_F;
  if (p < N) {
    const float* rp = rowPart + p;
    for (int c = 0; c < NCHUNKS; c += 4) {
      m0 = fminf(m0, rp[(size_t)(c + 0) * N]);
      m1 = fminf(m1, rp[(size_t)(c + 1) * N]);
      m2 = fminf(m2, rp[(size_t)(c + 2) * N]);
      m3 = fminf(m3, rp[(size_t)(c + 3) * N]);
    }
  } else {
    const float* cp = colPart + (p - N);
    for (int s = 0; s < NSTRIPS; s += 4) {
      m0 = fminf(m0, cp[(size_t)(s + 0) * N]);
      m1 = fminf(m1, cp[(size_t)(s + 1) * N]);
      m2 = fminf(m2, cp[(size_t)(s + 2) * N]);
      m3 = fminf(m3, cp[(size_t)(s + 3) * N]);
    }
  }
  float d = sqrtf(fmaxf(fminf(fminf(m0, m1), fminf(m2, m3)), 0.0f));

  for (int off = 32; off > 0; off >>= 1) d += __shfl_down(d, off, 64);
  __shared__ float red[THREADS / 64];
  const int wave = threadIdx.x >> 6;
  const int lane = threadIdx.x & 63;
  if (lane == 0) red[wave] = d;
  __syncthreads();
  if (threadIdx.x == 0) {
    float s = 0.0f;
    for (int wv = 0; wv < THREADS / 64; ++wv) s += red[wv];
    atomicAdd(out, s);
  }
}

extern "C" void kernel_launch(void* const* d_in, const int* in_sizes, int n_in,
                              void* d_out, int out_size, void* d_ws, size_t ws_size,
                              hipStream_t stream) {
  const float* p1 = (const float*)d_in[0];
  const float* p2 = (const float*)d_in[1];
  float* out = (float*)d_out;
  float* ws = (float*)d_ws;

  // ws: rowPart[NCHUNKS=16][N] (1MB) + colPart[NSTRIPS=64][N] (4MB).
  float* rowPart = ws;
  float* colPart = ws + (size_t)NCHUNKS * N;

  chamfer_mfma<<<dim3(NSTRIPS * NCHUNKS), THREADS, 0, stream>>>(
      p1, p2, rowPart, colPart, out);
  chamfer_sum<<<dim3((2 * N) / THREADS), THREADS, 0, stream>>>(rowPart, colPart,
                                                               out);
}